// Round 19
// baseline (113.809 us; speedup 1.0000x reference)
//
#include <hip/hip_runtime.h>
#include <math.h>

typedef float f32x4 __attribute__((ext_vector_type(4)));
typedef short short8 __attribute__((ext_vector_type(8)));

__device__ __forceinline__ short bf16r(float f) {
    union { float f; unsigned u; } x; x.f = f;
    unsigned u = x.u + 0x7fffu + ((x.u >> 16) & 1u);
    return (short)(u >> 16);
}

// ---------------------------------------------------------------------------
// pack_kernel (16x16x32 format, verified r1-r18)
// ---------------------------------------------------------------------------
template<int K>
__device__ __forceinline__ void pack_branch(const float* __restrict__ w2,
                                            short* __restrict__ wpack, int u) {
    int lane = u & 63;
    int kb   = (u >> 6) & 1;
    int rem  = u >> 7;          // c*K + j
    int j = rem % K, c = rem / K;
    int co  = c * 16 + (lane & 15);
    int cib = kb * 32 + 8 * ((lane >> 4) & 3);
    short8 v;
    #pragma unroll
    for (int i = 0; i < 8; ++i)
        v[i] = bf16r(w2[(co * 64 + (cib + i)) * K + j]);
    *reinterpret_cast<short8*>(wpack + (size_t)u * 8) = v;
}

__global__ __launch_bounds__(256) void pack_kernel(
    const float* __restrict__ w23, const float* __restrict__ w25,
    const float* __restrict__ w27,
    short* __restrict__ wp3, short* __restrict__ wp5, short* __restrict__ wp7)
{
    int tid = blockIdx.x * 256 + threadIdx.x;
    const int n3 = 8 * 3 * 2 * 64;   // 3072
    const int n5 = 8 * 5 * 2 * 64;   // 5120
    const int n7 = 8 * 7 * 2 * 64;   // 7168
    if (tid < n3)                pack_branch<3>(w23, wp3, tid);
    else if (tid < n3 + n5)      pack_branch<5>(w25, wp5, tid - n3);
    else if (tid < n3 + n5 + n7) pack_branch<7>(w27, wp7, tid - n3 - n5);
}

// ---------------------------------------------------------------------------
// mfma_pass2<K,LT0,NLT>: dual-c lt-pass, rolled m-loop + named 1-deep B
// prefetch (spill-safe, r13/r14-verified). One A-read feeds 2 MFMAs.
// ---------------------------------------------------------------------------
template<int K, int LT0, int NLT>
__device__ __forceinline__ void mfma_pass2(
    const short* __restrict__ t1s,
    const short8* __restrict__ wpB0, const short8* __restrict__ wpB1,
    int lane, f32x4* accA, f32x4* accB)
{
    constexpr int PAD = (K - 1) / 2;
    const int lane15 = lane & 15;
    const int g8 = 8 * ((lane >> 4) & 3);
    short8 bA = wpB0[0], bB = wpB1[0];
    #pragma unroll 1
    for (int m = 0; m < 2 * K - 1; ++m) {
        const short8 nA = wpB0[(m + 1) * 64];
        const short8 nB = wpB1[(m + 1) * 64];
        const int j = m >> 1, kb = m & 1;
        const int r = LT0 * 16 + lane15 + 3 + j - PAD;
        const int col = (kb * 32 + g8) ^ ((r & 7) << 3);
        const short* ab = &t1s[r * 64 + col];
        #pragma unroll
        for (int lt = 0; lt < NLT; ++lt) {
            const short8 af = *reinterpret_cast<const short8*>(ab + lt * 1024);
            accA[lt] = __builtin_amdgcn_mfma_f32_16x16x32_bf16(af, bA, accA[lt], 0, 0, 0);
            accB[lt] = __builtin_amdgcn_mfma_f32_16x16x32_bf16(af, bB, accB[lt], 0, 0, 0);
        }
        bA = nA; bB = nB;
    }
    {   // peeled last group
        const int m = 2 * K - 1;
        const int j = m >> 1, kb = m & 1;
        const int r = LT0 * 16 + lane15 + 3 + j - PAD;
        const int col = (kb * 32 + g8) ^ ((r & 7) << 3);
        const short* ab = &t1s[r * 64 + col];
        #pragma unroll
        for (int lt = 0; lt < NLT; ++lt) {
            const short8 af = *reinterpret_cast<const short8*>(ab + lt * 1024);
            accA[lt] = __builtin_amdgcn_mfma_f32_16x16x32_bf16(af, bA, accA[lt], 0, 0, 0);
            accB[lt] = __builtin_amdgcn_mfma_f32_16x16x32_bf16(af, bB, accB[lt], 0, 0, 0);
        }
    }
}

// pool_accum<GV,LT0,NLT>: C/D col=lane&15, row=4g+r4 (verified r1-r18).
template<int GV, int LT0, int NLT>
__device__ __forceinline__ void pool_accum(const f32x4* acc, float bb, float* pb) {
    #pragma unroll
    for (int lt = 0; lt < NLT; ++lt) {
        #pragma unroll
        for (int r4 = 0; r4 < 4; ++r4) {
            const int l = (LT0 + lt) * 16 + 4 * GV + r4;   // compile-time
            if (l < 200)
                pb[l / 20] += fmaxf(acc[lt][r4] + bb, 0.0f);
        }
    }
}

template<int K, int LT0, int NLT>
__device__ __forceinline__ void do_pass2(
    const short* __restrict__ t1s,
    const short8* __restrict__ wpB0, const short8* __restrict__ wpB1,
    int lane, float bb0, float bb1, float* pb0, float* pb1)
{
    const int g = (lane >> 4) & 3;
    f32x4 accA[NLT], accB[NLT];
    #pragma unroll
    for (int i = 0; i < NLT; ++i) {
        f32x4 z = {0.f, 0.f, 0.f, 0.f};
        accA[i] = z; accB[i] = z;
    }
    mfma_pass2<K, LT0, NLT>(t1s, wpB0, wpB1, lane, accA, accB);
    if      (g == 0) { pool_accum<0, LT0, NLT>(accA, bb0, pb0); pool_accum<0, LT0, NLT>(accB, bb1, pb1); }
    else if (g == 1) { pool_accum<1, LT0, NLT>(accA, bb0, pb0); pool_accum<1, LT0, NLT>(accB, bb1, pb1); }
    else if (g == 2) { pool_accum<2, LT0, NLT>(accA, bb0, pb0); pool_accum<2, LT0, NLT>(accB, bb1, pb1); }
    else             { pool_accum<3, LT0, NLT>(accA, bb0, pb0); pool_accum<3, LT0, NLT>(accB, bb1, pb1); }
}

// ---------------------------------------------------------------------------
// branch_body<K>: producer path, r14 numerics; only the final xfeatP store is
// now a device-scope RELAXED ATOMIC store (cache-bypassing, no fence needed).
// ---------------------------------------------------------------------------
template<int K>
__device__ __forceinline__ void branch_body(
    const int bn, const int t,
    const float* __restrict__ x,
    const float* __restrict__ w1, const float* __restrict__ b1,
    const float* __restrict__ b2, const short* __restrict__ wpack,
    const float* __restrict__ w_xfc_br, float* __restrict__ xfeatP_br,
    float* xs, short* t1s, float* pooled_s, float* b2s)
{
    constexpr int PAD = (K - 1) / 2;
    const int lane = t & 63;
    const int w    = t >> 6;            // 0..3, owns c = 2w, 2w+1
    const int lane15 = lane & 15;

    if (t < 208) xs[t] = 0.0f;
    for (int idx = t; idx < 32 * 64; idx += 256) {  // halo rows 0..2, 203..231
        int rr = idx >> 6;
        int row = (rr < 3) ? rr : (200 + rr);
        t1s[row * 64 + (idx & 63)] = 0;
    }
    if (t < 128) b2s[t] = b2[t];
    __syncthreads();

    if (t < 200) xs[3 + t] = x[bn * 200 + t];
    __syncthreads();

    // conv1, register-window (wave-uniform broadcast reads)
    {
        float w1_0 = w1[lane * K + 0], w1_1 = w1[lane * K + 1], w1_2 = w1[lane * K + 2];
        float w1_3 = 0.f, w1_4 = 0.f, w1_5 = 0.f, w1_6 = 0.f;
        if (K > 3) { w1_3 = w1[lane * K + 3]; w1_4 = w1[lane * K + 4]; }
        if (K > 5) { w1_5 = w1[lane * K + 5]; w1_6 = w1[lane * K + 6]; }
        const float b1r = b1[lane];
        #pragma unroll 1
        for (int ch = 0; ch < 2; ++ch) {
            const int lb = 50 * w + 25 * ch;       // wave-uniform base
            float xr[31];
            #pragma unroll
            for (int i = 0; i < 31; ++i) xr[i] = xs[lb + i];   // broadcast reads
            #pragma unroll
            for (int ll = 0; ll < 25; ++ll) {
                float a = b1r;
                a = fmaf(w1_0, xr[ll + 3 - PAD + 0], a);
                a = fmaf(w1_1, xr[ll + 3 - PAD + 1], a);
                a = fmaf(w1_2, xr[ll + 3 - PAD + 2], a);
                if (K > 3) {
                    a = fmaf(w1_3, xr[ll + 3 - PAD + 3], a);
                    a = fmaf(w1_4, xr[ll + 3 - PAD + 4], a);
                }
                if (K > 5) {
                    a = fmaf(w1_5, xr[ll + 3 - PAD + 5], a);
                    a = fmaf(w1_6, xr[ll + 3 - PAD + 6], a);
                }
                const int row = lb + ll + 3;
                t1s[row * 64 + (lane ^ ((row & 7) << 3))] = bf16r(fmaxf(a, 0.0f));
            }
        }
    }
    __syncthreads();

    const int c0 = 2 * w, c1 = 2 * w + 1;
    const int coA = c0 * 16 + lane15, coB = c1 * 16 + lane15;
    const float bb0 = b2s[coA], bb1 = b2s[coB];
    const short8* wpB0 = reinterpret_cast<const short8*>(wpack)
                         + (size_t)(c0 * 2 * K) * 64 + lane;
    const short8* wpB1 = reinterpret_cast<const short8*>(wpack)
                         + (size_t)(c1 * 2 * K) * 64 + lane;

    float pb0[10], pb1[10];
    #pragma unroll
    for (int b = 0; b < 10; ++b) { pb0[b] = 0.0f; pb1[b] = 0.0f; }

    do_pass2<K, 0, 7>(t1s, wpB0, wpB1, lane, bb0, bb1, pb0, pb1);
    do_pass2<K, 7, 6>(t1s, wpB0, wpB1, lane, bb0, bb1, pb0, pb1);

    #pragma unroll
    for (int b = 0; b < 10; ++b) {
        pb0[b] += __shfl_xor(pb0[b], 16);
        pb0[b] += __shfl_xor(pb0[b], 32);
        pb1[b] += __shfl_xor(pb1[b], 16);
        pb1[b] += __shfl_xor(pb1[b], 32);
    }
    if (lane < 16) {
        #pragma unroll
        for (int b = 0; b < 10; ++b) {
            pooled_s[coA * 10 + b] = pb0[b];
            pooled_s[coB * 10 + b] = pb1[b];
        }
    }
    __syncthreads();

    // xfc partial: o = t>>3 (0..31), part = t&7; coalesced f32x4
    {
        const int o = t >> 3, part = t & 7;
        const f32x4* wr4 = reinterpret_cast<const f32x4*>(w_xfc_br + o * 3840);
        const f32x4* pp4 = reinterpret_cast<const f32x4*>(pooled_s);
        float s0 = 0.0f, s1 = 0.0f;
        #pragma unroll
        for (int i = 0; i < 40; ++i) {
            const f32x4 wv = wr4[part + 8 * i];
            const f32x4 pv = pp4[part + 8 * i];
            float s = wv[0] * pv[0];
            s = fmaf(wv[1], pv[1], s);
            s = fmaf(wv[2], pv[2], s);
            s = fmaf(wv[3], pv[3], s);
            if (i & 1) s1 += s; else s0 += s;
        }
        float a = s0 + s1;
        a += __shfl_xor(a, 1);
        a += __shfl_xor(a, 2);
        a += __shfl_xor(a, 4);
        if (part == 0)
            __hip_atomic_store(&xfeatP_br[bn * 32 + o], a * 0.05f,
                               __ATOMIC_RELAXED, __HIP_MEMORY_SCOPE_AGENT);
    }
}

// ---------------------------------------------------------------------------
// tail_body: r14's verified fast (unrolled f32x4) tail, LDS carved from smem.
// xfeatP read via relaxed device-scope atomic loads (bypass stale local L2).
// ---------------------------------------------------------------------------
__device__ void tail_body(
    const int b, const int t, char* smem,
    const float* __restrict__ xfeatP, const float* __restrict__ b_xfc,
    const float* __restrict__ xmaskp, const float* __restrict__ elem_info,
    const float* __restrict__ emaskp,
    const float* __restrict__ w_float, const float* __restrict__ b_float,
    const float* __restrict__ atom_emb, const float* __restrict__ type_emb,
    const float* __restrict__ w_fuse,  const float* __restrict__ b_fuse,
    const float* __restrict__ in_w,    const float* __restrict__ in_b,
    const float* __restrict__ out_w,   const float* __restrict__ out_b,
    const float* __restrict__ w_fc1,   const float* __restrict__ b_fc1,
    const float* __restrict__ w_fc2,   const float* __restrict__ b_fc2,
    float* __restrict__ out)
{
    typedef float fu_t[60];
    typedef float f64_t[64];
    typedef float q_t[196];
    typedef float sc_t[16][16];
    fu_t*  fu    = (fu_t*) (smem + 0);       // 3840
    f64_t* fused = (f64_t*)(smem + 3840);    // 4096
    q_t*   qkvs  = (q_t*)  (smem + 7936);    // 12544
    sc_t*  sc    = (sc_t*) (smem + 20480);   // 4096
    f64_t* ao    = (f64_t*)(smem + 24576);   // 4096
    f64_t* aoo   = (f64_t*)(smem + 28672);   // 4096
    float* p2s   = (float*)(smem + 32768);   // 256
    float* hs    = (float*)(smem + 33024);   // 256
    float* em    = (float*)(smem + 33280);   // 64

    if (t < 16) em[t] = emaskp[b * 16 + t];

    for (int d = t; d < 512; d += 256) {
        int n = d >> 5, o = d & 31;
        const int bn = b * 16 + n;
        float a = __hip_atomic_load(&xfeatP[bn * 32 + o],
                                    __ATOMIC_RELAXED, __HIP_MEMORY_SCOPE_AGENT)
                + __hip_atomic_load(&xfeatP[(512 + bn) * 32 + o],
                                    __ATOMIC_RELAXED, __HIP_MEMORY_SCOPE_AGENT)
                + __hip_atomic_load(&xfeatP[(1024 + bn) * 32 + o],
                                    __ATOMIC_RELAXED, __HIP_MEMORY_SCOPE_AGENT);
        fu[n][o] = (a + b_xfc[o]) * xmaskp[bn];
    }
    {
        int n = t >> 4, slot = t & 15;
        float m  = emaskp[b * 16 + n];
        float vE = (m >= 0.5f) ? 1.0f : 0.0f;
        const float* ei = elem_info + (b * 16 + n) * 7;
        float a = b_float[slot];
        #pragma unroll
        for (int i = 0; i < 5; ++i)
            a = fmaf(ei[i] * m, w_float[slot * 5 + i], a);
        fu[n][32 + slot] = fmaxf(a, 0.0f) * vE * m;

        int an = (int)(ei[5] * m);
        int et = (int)(ei[6] * m);
        float take = (vE != 0.0f && an >= 1 && an <= 94) ? 1.0f : 0.0f;
        int anc = an < 0 ? 0 : (an > 94 ? 94 : an);
        int etc = et < 0 ? 0 : (et > 5 ? 5 : et);
        if (slot < 8)
            fu[n][48 + slot] = atom_emb[anc * 8 + slot] * take * m;
        else if (slot < 12)
            fu[n][56 + (slot - 8)] = type_emb[etc * 4 + (slot - 8)] * take * m;
    }
    __syncthreads();

    for (int d = t; d < 1024; d += 256) {
        int n = d >> 6, o = d & 63;
        const f32x4* wr4 = reinterpret_cast<const f32x4*>(w_fuse + o * 60);
        const f32x4* fr4 = reinterpret_cast<const f32x4*>(&fu[n][0]);
        float a0 = b_fuse[o], a1 = 0.0f;
        #pragma unroll
        for (int i = 0; i < 15; ++i) {
            const f32x4 wv = wr4[i];
            const f32x4 fv = fr4[i];
            float s = wv[0] * fv[0];
            s = fmaf(wv[1], fv[1], s);
            s = fmaf(wv[2], fv[2], s);
            s = fmaf(wv[3], fv[3], s);
            if (i & 1) a1 += s; else a0 += s;
        }
        fused[n][o] = (a0 + a1) * em[n];
    }
    __syncthreads();

    for (int d = t; d < 3072; d += 256) {
        int n = d / 192, rr = d - n * 192;
        const f32x4* wr4 = reinterpret_cast<const f32x4*>(in_w + rr * 64);
        const f32x4* fr4 = reinterpret_cast<const f32x4*>(&fused[n][0]);
        float a0 = in_b[rr], a1 = 0.0f;
        #pragma unroll
        for (int i = 0; i < 16; ++i) {
            const f32x4 wv = wr4[i];
            const f32x4 fv = fr4[i];
            float s = wv[0] * fv[0];
            s = fmaf(wv[1], fv[1], s);
            s = fmaf(wv[2], fv[2], s);
            s = fmaf(wv[3], fv[3], s);
            if (i & 1) a1 += s; else a0 += s;
        }
        qkvs[n][rr] = a0 + a1;
    }
    __syncthreads();

    for (int d = t; d < 1024; d += 256) {
        int h = d >> 8, i = (d >> 4) & 15, j = d & 15;
        const f32x4* qi = reinterpret_cast<const f32x4*>(&qkvs[i][h * 16]);
        const f32x4* kj = reinterpret_cast<const f32x4*>(&qkvs[j][64 + h * 16]);
        float a = 0.0f;
        #pragma unroll
        for (int q4 = 0; q4 < 4; ++q4) {
            const f32x4 qv = qi[q4];
            const f32x4 kv = kj[q4];
            a = fmaf(qv[0], kv[0], a);
            a = fmaf(qv[1], kv[1], a);
            a = fmaf(qv[2], kv[2], a);
            a = fmaf(qv[3], kv[3], a);
        }
        a *= 0.25f;
        if (em[j] < 0.5f) a = -1e30f;
        sc[h][i][j] = a;
    }
    __syncthreads();

    if (t < 64) {
        int h = t >> 4, i = t & 15;
        float mx = -3.4e38f;
        #pragma unroll
        for (int j = 0; j < 16; ++j) mx = fmaxf(mx, sc[h][i][j]);
        float e[16];
        float s = 0.0f;
        #pragma unroll
        for (int j = 0; j < 16; ++j) { e[j] = expf(sc[h][i][j] - mx); s += e[j]; }
        float inv = 1.0f / s;
        #pragma unroll
        for (int j = 0; j < 16; ++j) sc[h][i][j] = e[j] * inv;
    }
    __syncthreads();

    for (int d = t; d < 1024; d += 256) {
        int n = d >> 6, e = d & 63, h = e >> 4;
        float a = 0.0f;
        #pragma unroll
        for (int j = 0; j < 16; ++j)
            a = fmaf(sc[h][n][j], qkvs[j][128 + e], a);
        ao[n][e] = a;
    }
    __syncthreads();

    for (int d = t; d < 1024; d += 256) {
        int n = d >> 6, o = d & 63;
        const f32x4* wr4 = reinterpret_cast<const f32x4*>(out_w + o * 64);
        const f32x4* ar4 = reinterpret_cast<const f32x4*>(&ao[n][0]);
        float a0 = out_b[o], a1 = 0.0f;
        #pragma unroll
        for (int i = 0; i < 16; ++i) {
            const f32x4 wv = wr4[i];
            const f32x4 av = ar4[i];
            float s = wv[0] * av[0];
            s = fmaf(wv[1], av[1], s);
            s = fmaf(wv[2], av[2], s);
            s = fmaf(wv[3], av[3], s);
            if (i & 1) a1 += s; else a0 += s;
        }
        aoo[n][o] = (a0 + a1) * em[n];
    }
    __syncthreads();

    if (t < 64) {
        float s = 0.0f, ms = 0.0f;
        #pragma unroll
        for (int n = 0; n < 16; ++n) { s += aoo[n][t]; ms += em[n]; }
        p2s[t] = s / (ms + 1e-8f);
    }
    __syncthreads();

    if (t < 64) {
        const f32x4* wr4 = reinterpret_cast<const f32x4*>(w_fc1 + t * 64);
        const f32x4* pr4 = reinterpret_cast<const f32x4*>(p2s);
        float a0 = b_fc1[t], a1 = 0.0f;
        #pragma unroll
        for (int i = 0; i < 16; ++i) {
            const f32x4 wv = wr4[i];
            const f32x4 pv = pr4[i];
            float s = wv[0] * pv[0];
            s = fmaf(wv[1], pv[1], s);
            s = fmaf(wv[2], pv[2], s);
            s = fmaf(wv[3], pv[3], s);
            if (i & 1) a1 += s; else a0 += s;
        }
        hs[t] = fmaxf(a0 + a1, 0.0f);
    }
    __syncthreads();

    if (t < 64) {
        float v = hs[t] * w_fc2[t];
        #pragma unroll
        for (int d2 = 32; d2 >= 1; d2 >>= 1) v += __shfl_xor(v, d2);
        if (t == 0) out[b] = v + b_fc2[0];
    }
}

// ---------------------------------------------------------------------------
// mega: bx<1536 producers ((bn,br) branch, r14 path). bx>=1536: 32 consumers
// at the grid END (launched last -> producers nearly done; brief poll).
// Sync: producers do per-wave s_waitcnt vmcnt(0) + barrier + relaxed
// fetch_add (NO threadfence -> no L2-writeback storm, the r15/r16 killer).
// Consumers poll with relaxed atomic loads + s_sleep, then read xfeatP via
// relaxed atomic loads (coherent point; immune to stale L2 across replays).
// ---------------------------------------------------------------------------
__global__ __launch_bounds__(256, 4) void mega(
    const float* __restrict__ x, const float* __restrict__ xmask,
    const float* __restrict__ w1_3, const float* __restrict__ b1_3,
    const float* __restrict__ b2_3, const short* __restrict__ wp3,
    const float* __restrict__ w1_5, const float* __restrict__ b1_5,
    const float* __restrict__ b2_5, const short* __restrict__ wp5,
    const float* __restrict__ w1_7, const float* __restrict__ b1_7,
    const float* __restrict__ b2_7, const short* __restrict__ wp7,
    const float* __restrict__ w_xfc, float* __restrict__ xfeatP,
    unsigned* __restrict__ cnts,
    const float* __restrict__ b_xfc,
    const float* __restrict__ elem_info, const float* __restrict__ emaskp,
    const float* __restrict__ w_float, const float* __restrict__ b_float,
    const float* __restrict__ atom_emb, const float* __restrict__ type_emb,
    const float* __restrict__ w_fuse,  const float* __restrict__ b_fuse,
    const float* __restrict__ in_w,    const float* __restrict__ in_b,
    const float* __restrict__ out_w,   const float* __restrict__ out_b,
    const float* __restrict__ w_fc1,   const float* __restrict__ b_fc1,
    const float* __restrict__ w_fc2,   const float* __restrict__ b_fc2,
    float* __restrict__ out)
{
    __shared__ __align__(16) char smem[36608];
    const int bx = blockIdx.x;
    const int t  = threadIdx.x;

    if (bx < 1536) {
        // ---------------- producer ----------------
        const int br = bx % 3;
        const int bn = bx / 3;
        const int b  = bn >> 4;

        float* xs       = (float*)(smem + 0);       // 832
        short* t1s      = (short*)(smem + 832);     // 29696
        float* pooled_s = (float*)(smem + 30528);   // 5120
        float* b2s      = (float*)(smem + 35648);   // 512

        if (xmask[bn] != 0.0f) {                    // block-uniform condition
            if (br == 0)
                branch_body<3>(bn, t, x, w1_3, b1_3, b2_3, wp3,
                               w_xfc,        xfeatP,             xs, t1s, pooled_s, b2s);
            else if (br == 1)
                branch_body<5>(bn, t, x, w1_5, b1_5, b2_5, wp5,
                               w_xfc + 1280, xfeatP + 512 * 32,  xs, t1s, pooled_s, b2s);
            else
                branch_body<7>(bn, t, x, w1_7, b1_7, b2_7, wp7,
                               w_xfc + 2560, xfeatP + 1024 * 32, xs, t1s, pooled_s, b2s);
        }
        // release: per-wave store completion, then one relaxed signal
        asm volatile("s_waitcnt vmcnt(0)" ::: "memory");
        __syncthreads();
        if (t == 0)
            __hip_atomic_fetch_add(&cnts[b], 1u,
                                   __ATOMIC_RELAXED, __HIP_MEMORY_SCOPE_AGENT);
        return;
    }

    // ---------------- consumer ----------------
    const int b = bx - 1536;
    if (t == 0) {
        while (__hip_atomic_load(&cnts[b], __ATOMIC_RELAXED,
                                 __HIP_MEMORY_SCOPE_AGENT) < 48u)
            __builtin_amdgcn_s_sleep(16);
    }
    __syncthreads();   // all threads held until signal; loads below issue after
    tail_body(b, t, smem, xfeatP, b_xfc, xmask, elem_info, emaskp,
              w_float, b_float, atom_emb, type_emb, w_fuse, b_fuse,
              in_w, in_b, out_w, out_b, w_fc1, b_fc1, w_fc2, b_fc2, out);
}

extern "C" void kernel_launch(void* const* d_in, const int* in_sizes, int n_in,
                              void* d_out, int out_size, void* d_ws, size_t ws_size,
                              hipStream_t stream)
{
    (void)in_sizes; (void)n_in; (void)out_size; (void)ws_size;
    const float* x     = (const float*)d_in[0];
    const float* xmask = (const float*)d_in[1];
    const float* einfo = (const float*)d_in[2];
    const float* emask = (const float*)d_in[3];

    float*    xfeatP = (float*)d_ws;                    // 196608 B
    short*    wp3  = (short*)((char*)d_ws + 196608);    // 49152 B
    short*    wp5  = wp3 + 24576;                       // 81920 B
    short*    wp7  = wp5 + 40960;                       // 114688 B
    unsigned* cnts = (unsigned*)((char*)d_ws + 442368); // 128 B

    hipMemsetAsync(cnts, 0, 32 * sizeof(unsigned), stream);

    pack_kernel<<<60, 256, 0, stream>>>(
        (const float*)d_in[6], (const float*)d_in[10], (const float*)d_in[14],
        wp3, wp5, wp7);

    mega<<<1568, 256, 0, stream>>>(x, xmask,
        (const float*)d_in[4],  (const float*)d_in[5],  (const float*)d_in[7],  wp3,
        (const float*)d_in[8],  (const float*)d_in[9],  (const float*)d_in[11], wp5,
        (const float*)d_in[12], (const float*)d_in[13], (const float*)d_in[15], wp7,
        (const float*)d_in[16], xfeatP, cnts,
        (const float*)d_in[17], einfo, emask,
        (const float*)d_in[18], (const float*)d_in[19],
        (const float*)d_in[20], (const float*)d_in[21],
        (const float*)d_in[22], (const float*)d_in[23],
        (const float*)d_in[24], (const float*)d_in[25],
        (const float*)d_in[26], (const float*)d_in[27],
        (const float*)d_in[28], (const float*)d_in[29],
        (const float*)d_in[30], (const float*)d_in[31],
        (float*)d_out);
}

// Round 20
// 71.315 us; speedup vs baseline: 1.5959x; 1.5959x over previous
//
#include <hip/hip_runtime.h>
#include <math.h>

typedef float f32x4 __attribute__((ext_vector_type(4)));
typedef short short8 __attribute__((ext_vector_type(8)));

__device__ __forceinline__ short bf16r(float f) {
    union { float f; unsigned u; } x; x.f = f;
    unsigned u = x.u + 0x7fffu + ((x.u >> 16) & 1u);
    return (short)(u >> 16);
}

// ---------------------------------------------------------------------------
// pack_kernel (16x16x32 format, verified r1-r19)
// ---------------------------------------------------------------------------
template<int K>
__device__ __forceinline__ void pack_branch(const float* __restrict__ w2,
                                            short* __restrict__ wpack, int u) {
    int lane = u & 63;
    int kb   = (u >> 6) & 1;
    int rem  = u >> 7;          // c*K + j
    int j = rem % K, c = rem / K;
    int co  = c * 16 + (lane & 15);
    int cib = kb * 32 + 8 * ((lane >> 4) & 3);
    short8 v;
    #pragma unroll
    for (int i = 0; i < 8; ++i)
        v[i] = bf16r(w2[(co * 64 + (cib + i)) * K + j]);
    *reinterpret_cast<short8*>(wpack + (size_t)u * 8) = v;
}

__global__ __launch_bounds__(256) void pack_kernel(
    const float* __restrict__ w23, const float* __restrict__ w25,
    const float* __restrict__ w27,
    short* __restrict__ wp3, short* __restrict__ wp5, short* __restrict__ wp7)
{
    int tid = blockIdx.x * 256 + threadIdx.x;
    const int n3 = 8 * 3 * 2 * 64;   // 3072
    const int n5 = 8 * 5 * 2 * 64;   // 5120
    const int n7 = 8 * 7 * 2 * 64;   // 7168
    if (tid < n3)                pack_branch<3>(w23, wp3, tid);
    else if (tid < n3 + n5)      pack_branch<5>(w25, wp5, tid - n3);
    else if (tid < n3 + n5 + n7) pack_branch<7>(w27, wp7, tid - n3 - n5);
}

// ---------------------------------------------------------------------------
// mfma_pass2<K,NLT>: dual-c pass over NLT tiles, LOCAL row base 0.
// Rolled m-loop + named 1-deep B prefetch (spill-safe, r13/r14-verified).
// One A-read feeds 2 MFMAs.
// ---------------------------------------------------------------------------
template<int K, int NLT>
__device__ __forceinline__ void mfma_pass2(
    const short* __restrict__ t1s,
    const short8* __restrict__ wpB0, const short8* __restrict__ wpB1,
    int lane, f32x4* accA, f32x4* accB)
{
    constexpr int PAD = (K - 1) / 2;
    const int lane15 = lane & 15;
    const int g8 = 8 * ((lane >> 4) & 3);
    short8 bA = wpB0[0], bB = wpB1[0];
    #pragma unroll 1
    for (int m = 0; m < 2 * K - 1; ++m) {
        const short8 nA = wpB0[(m + 1) * 64];
        const short8 nB = wpB1[(m + 1) * 64];
        const int j = m >> 1, kb = m & 1;
        const int r = lane15 + 3 + j - PAD;              // local row, tile 0
        const int col = (kb * 32 + g8) ^ ((r & 7) << 3); // tile-invariant swz
        const short* ab = &t1s[r * 64 + col];
        #pragma unroll
        for (int lt = 0; lt < NLT; ++lt) {
            const short8 af = *reinterpret_cast<const short8*>(ab + lt * 1024);
            accA[lt] = __builtin_amdgcn_mfma_f32_16x16x32_bf16(af, bA, accA[lt], 0, 0, 0);
            accB[lt] = __builtin_amdgcn_mfma_f32_16x16x32_bf16(af, bB, accB[lt], 0, 0, 0);
        }
        bA = nA; bB = nB;
    }
    {   // peeled last group
        const int m = 2 * K - 1;
        const int j = m >> 1, kb = m & 1;
        const int r = lane15 + 3 + j - PAD;
        const int col = (kb * 32 + g8) ^ ((r & 7) << 3);
        const short* ab = &t1s[r * 64 + col];
        #pragma unroll
        for (int lt = 0; lt < NLT; ++lt) {
            const short8 af = *reinterpret_cast<const short8*>(ab + lt * 1024);
            accA[lt] = __builtin_amdgcn_mfma_f32_16x16x32_bf16(af, bA, accA[lt], 0, 0, 0);
            accB[lt] = __builtin_amdgcn_mfma_f32_16x16x32_bf16(af, bB, accB[lt], 0, 0, 0);
        }
    }
}

// pool_accum<GV,LT0,NLT>: GLOBAL tile base LT0; C/D col=lane&15, row=4g+r4
// (verified r1-r19). l = global position; bins exact by linearity.
template<int GV, int LT0, int NLT>
__device__ __forceinline__ void pool_accum(const f32x4* acc, float bb, float* pb) {
    #pragma unroll
    for (int lt = 0; lt < NLT; ++lt) {
        #pragma unroll
        for (int r4 = 0; r4 < 4; ++r4) {
            const int l = (LT0 + lt) * 16 + 4 * GV + r4;   // compile-time
            if (l < 200)
                pb[l / 20] += fmaxf(acc[lt][r4] + bb, 0.0f);
        }
    }
}

template<int K, int LT0, int NLT>
__device__ __forceinline__ void do_pass2(
    const short* __restrict__ t1s,
    const short8* __restrict__ wpB0, const short8* __restrict__ wpB1,
    int lane, float bb0, float bb1, float* pb0, float* pb1)
{
    const int g = (lane >> 4) & 3;
    f32x4 accA[NLT], accB[NLT];
    #pragma unroll
    for (int i = 0; i < NLT; ++i) {
        f32x4 z = {0.f, 0.f, 0.f, 0.f};
        accA[i] = z; accB[i] = z;
    }
    mfma_pass2<K, NLT>(t1s, wpB0, wpB1, lane, accA, accB);
    if      (g == 0) { pool_accum<0, LT0, NLT>(accA, bb0, pb0); pool_accum<0, LT0, NLT>(accB, bb1, pb1); }
    else if (g == 1) { pool_accum<1, LT0, NLT>(accA, bb0, pb0); pool_accum<1, LT0, NLT>(accB, bb1, pb1); }
    else if (g == 2) { pool_accum<2, LT0, NLT>(accA, bb0, pb0); pool_accum<2, LT0, NLT>(accB, bb1, pb1); }
    else             { pool_accum<3, LT0, NLT>(accA, bb0, pb0); pool_accum<3, LT0, NLT>(accB, bb1, pb1); }
}

// ---------------------------------------------------------------------------
// branch_body<K,HALF>: half an (bn,branch) l-range per block.
//   HALF=0: tiles lt 0..5  (l 0..95);  HALF=1: tiles lt 6..12 (l 96..199).
//   Local row = l - ROFF (ROFF = -3 / 93): the MFMA local-row formula is
//   identical for both halves (L0 - ROFF = 3). Partial pool bins + partial
//   xfc slice are exact by linearity; tail sums 6 slices.
//   t1s is 120 rows (15.4KB) -> ~21.8KB LDS/block -> 7 blocks/CU.
// ---------------------------------------------------------------------------
template<int K, int HALF>
__device__ __forceinline__ void branch_body(
    const int bn, const int t,
    const float* __restrict__ x,
    const float* __restrict__ w1, const float* __restrict__ b1,
    const float* __restrict__ b2, const short* __restrict__ wpack,
    const float* __restrict__ w_xfc_br, float* __restrict__ xfeatP_sl,
    float* xs, short* t1s, float* pooled_s, float* b2s)
{
    constexpr int PAD  = (K - 1) / 2;
    constexpr int ROFF = HALF ? 93 : -3;     // local row = l - ROFF
    constexpr int C0   = HALF ? 93 : 0;      // conv1 l-range
    constexpr int C1   = HALF ? 200 : 99;
    constexpr int LT0  = HALF ? 6 : 0;       // global tile base
    constexpr int NT   = HALF ? 7 : 6;

    const int lane = t & 63;
    const int w    = t >> 6;                 // 0..3, owns c = 2w, 2w+1
    const int lane15 = lane & 15;

    // ---- P0: zero halo rows {0,1,2, 107..119}, preload b2, load x ----
    if (t < 208) xs[t] = 0.0f;
    for (int idx = t; idx < 16 * 64; idx += 256) {
        int rr = idx >> 6;
        int row = (rr < 3) ? rr : (104 + rr);   // 0..2, 107..119
        t1s[row * 64 + (idx & 63)] = 0;
    }
    if (t < 128) b2s[t] = b2[t];
    __syncthreads();

    if (t < 200) xs[3 + t] = x[bn * 200 + t];
    __syncthreads();

    // ---- P1: conv1 (ci = lane, l strided by 4 waves), bf16 swizzled ----
    {
        float w1_0 = w1[lane * K + 0], w1_1 = w1[lane * K + 1], w1_2 = w1[lane * K + 2];
        float w1_3 = 0.f, w1_4 = 0.f, w1_5 = 0.f, w1_6 = 0.f;
        if (K > 3) { w1_3 = w1[lane * K + 3]; w1_4 = w1[lane * K + 4]; }
        if (K > 5) { w1_5 = w1[lane * K + 5]; w1_6 = w1[lane * K + 6]; }
        const float b1r = b1[lane];
        for (int l = C0 + w; l < C1; l += 4) {
            const float* xp = &xs[3 + l - PAD];
            float a = b1r;
            a = fmaf(w1_0, xp[0], a);
            a = fmaf(w1_1, xp[1], a);
            a = fmaf(w1_2, xp[2], a);
            if (K > 3) { a = fmaf(w1_3, xp[3], a); a = fmaf(w1_4, xp[4], a); }
            if (K > 5) { a = fmaf(w1_5, xp[5], a); a = fmaf(w1_6, xp[6], a); }
            const int row = l - ROFF;
            t1s[row * 64 + (lane ^ ((row & 7) << 3))] = bf16r(fmaxf(a, 0.0f));
        }
    }
    __syncthreads();

    // ---- P2: MFMA, dual-c, ONE pass of NT tiles ----
    const int c0 = 2 * w, c1 = 2 * w + 1;
    const int coA = c0 * 16 + lane15, coB = c1 * 16 + lane15;
    const float bb0 = b2s[coA], bb1 = b2s[coB];
    const short8* wpB0 = reinterpret_cast<const short8*>(wpack)
                         + (size_t)(c0 * 2 * K) * 64 + lane;
    const short8* wpB1 = reinterpret_cast<const short8*>(wpack)
                         + (size_t)(c1 * 2 * K) * 64 + lane;

    float pb0[10], pb1[10];
    #pragma unroll
    for (int b = 0; b < 10; ++b) { pb0[b] = 0.0f; pb1[b] = 0.0f; }

    do_pass2<K, LT0, NT>(t1s, wpB0, wpB1, lane, bb0, bb1, pb0, pb1);

    // ---- P3: reduce 4 co-sharing lanes; store pooled_s (linear) ----
    #pragma unroll
    for (int b = 0; b < 10; ++b) {
        pb0[b] += __shfl_xor(pb0[b], 16);
        pb0[b] += __shfl_xor(pb0[b], 32);
        pb1[b] += __shfl_xor(pb1[b], 16);
        pb1[b] += __shfl_xor(pb1[b], 32);
    }
    if (lane < 16) {
        #pragma unroll
        for (int b = 0; b < 10; ++b) {
            pooled_s[coA * 10 + b] = pb0[b];
            pooled_s[coB * 10 + b] = pb1[b];
        }
    }
    __syncthreads();

    // ---- P4: xfc partial (coalesced f32x4) -> this slice ----
    {
        const int o = t >> 3, part = t & 7;
        const f32x4* wr4 = reinterpret_cast<const f32x4*>(w_xfc_br + o * 3840);
        const f32x4* pp4 = reinterpret_cast<const f32x4*>(pooled_s);
        float s0 = 0.0f, s1 = 0.0f;
        #pragma unroll
        for (int i = 0; i < 40; ++i) {
            const f32x4 wv = wr4[part + 8 * i];
            const f32x4 pv = pp4[part + 8 * i];
            float s = wv[0] * pv[0];
            s = fmaf(wv[1], pv[1], s);
            s = fmaf(wv[2], pv[2], s);
            s = fmaf(wv[3], pv[3], s);
            if (i & 1) s1 += s; else s0 += s;
        }
        float a = s0 + s1;
        a += __shfl_xor(a, 1);
        a += __shfl_xor(a, 2);
        a += __shfl_xor(a, 4);
        if (part == 0) xfeatP_sl[bn * 32 + o] = a * 0.05f;
    }
}

__global__ __launch_bounds__(256, 4) void branch_fused(
    const float* __restrict__ x, const float* __restrict__ xmask,
    const float* __restrict__ w1_3, const float* __restrict__ b1_3,
    const float* __restrict__ b2_3, const short* __restrict__ wp3,
    const float* __restrict__ w1_5, const float* __restrict__ b1_5,
    const float* __restrict__ b2_5, const short* __restrict__ wp5,
    const float* __restrict__ w1_7, const float* __restrict__ b1_7,
    const float* __restrict__ b2_7, const short* __restrict__ wp7,
    const float* __restrict__ w_xfc, float* __restrict__ xfeatP)
{
    __shared__ float xs[208];
    __shared__ short t1s[120 * 64];
    __shared__ __align__(16) float pooled_s[1280];
    __shared__ float b2s[128];

    const int bx = blockIdx.x;
    const int s  = bx % 6;          // (br, half) interleaved every generation
    const int bn = bx / 6;
    const int br = s >> 1;
    const int hf = s & 1;
    const int t  = threadIdx.x;

    if (xmask[bn] == 0.0f) return;  // tail multiplies row by 0 -> exact

    float* sl = xfeatP + (size_t)s * 512 * 32;
    if (br == 0) {
        if (hf == 0) branch_body<3,0>(bn, t, x, w1_3, b1_3, b2_3, wp3, w_xfc,        sl, xs, t1s, pooled_s, b2s);
        else         branch_body<3,1>(bn, t, x, w1_3, b1_3, b2_3, wp3, w_xfc,        sl, xs, t1s, pooled_s, b2s);
    } else if (br == 1) {
        if (hf == 0) branch_body<5,0>(bn, t, x, w1_5, b1_5, b2_5, wp5, w_xfc + 1280, sl, xs, t1s, pooled_s, b2s);
        else         branch_body<5,1>(bn, t, x, w1_5, b1_5, b2_5, wp5, w_xfc + 1280, sl, xs, t1s, pooled_s, b2s);
    } else {
        if (hf == 0) branch_body<7,0>(bn, t, x, w1_7, b1_7, b2_7, wp7, w_xfc + 2560, sl, xs, t1s, pooled_s, b2s);
        else         branch_body<7,1>(bn, t, x, w1_7, b1_7, b2_7, wp7, w_xfc + 2560, sl, xs, t1s, pooled_s, b2s);
    }
}

// ---------------------------------------------------------------------------
// Tail (r14 numerics, 6-slice sum). Reported dur overlaps the branch drain
// (timestamp artifact); real work ~3us.
// ---------------------------------------------------------------------------
__global__ __launch_bounds__(256, 1) void tail_kernel(
    const float* __restrict__ xfeatP,     // (6, 512, 32)
    const float* __restrict__ b_xfc,      // (32,)
    const float* __restrict__ xmaskp,     // (512,)
    const float* __restrict__ elem_info,  // (32, 16, 7)
    const float* __restrict__ emaskp,     // (32, 16)
    const float* __restrict__ w_float, const float* __restrict__ b_float,
    const float* __restrict__ atom_emb, const float* __restrict__ type_emb,
    const float* __restrict__ w_fuse,  const float* __restrict__ b_fuse,
    const float* __restrict__ in_w,    const float* __restrict__ in_b,
    const float* __restrict__ out_w,   const float* __restrict__ out_b,
    const float* __restrict__ w_fc1,   const float* __restrict__ b_fc1,
    const float* __restrict__ w_fc2,   const float* __restrict__ b_fc2,
    float* __restrict__ out)              // (32,)
{
    const int b = blockIdx.x;
    const int t = threadIdx.x;

    __shared__ __align__(16) float fu[16][60];
    __shared__ __align__(16) float fused[16][64];
    __shared__ __align__(16) float qkvs[16][196];  // padded rows: 784B = 49*16
    __shared__ __align__(16) float sc[4][16][16];
    __shared__ __align__(16) float ao[16][64];
    __shared__ __align__(16) float aoo[16][64];
    __shared__ float p2s[64];
    __shared__ float hs[64];
    __shared__ float em[16];

    if (t < 16) em[t] = emaskp[b * 16 + t];

    for (int d = t; d < 512; d += 256) {
        int n = d >> 5, o = d & 31;
        const int bn = b * 16 + n;
        float a = 0.0f;
        #pragma unroll
        for (int s = 0; s < 6; ++s)
            a += xfeatP[(s * 512 + bn) * 32 + o];
        fu[n][o] = (a + b_xfc[o]) * xmaskp[bn];
    }
    {
        int n = t >> 4, slot = t & 15;
        float m  = emaskp[b * 16 + n];
        float vE = (m >= 0.5f) ? 1.0f : 0.0f;
        const float* ei = elem_info + (b * 16 + n) * 7;
        float a = b_float[slot];
        #pragma unroll
        for (int i = 0; i < 5; ++i)
            a = fmaf(ei[i] * m, w_float[slot * 5 + i], a);
        fu[n][32 + slot] = fmaxf(a, 0.0f) * vE * m;

        int an = (int)(ei[5] * m);
        int et = (int)(ei[6] * m);
        float take = (vE != 0.0f && an >= 1 && an <= 94) ? 1.0f : 0.0f;
        int anc = an < 0 ? 0 : (an > 94 ? 94 : an);
        int etc = et < 0 ? 0 : (et > 5 ? 5 : et);
        if (slot < 8)
            fu[n][48 + slot] = atom_emb[anc * 8 + slot] * take * m;
        else if (slot < 12)
            fu[n][56 + (slot - 8)] = type_emb[etc * 4 + (slot - 8)] * take * m;
    }
    __syncthreads();

    for (int d = t; d < 1024; d += 256) {
        int n = d >> 6, o = d & 63;
        const f32x4* wr4 = reinterpret_cast<const f32x4*>(w_fuse + o * 60);
        const f32x4* fr4 = reinterpret_cast<const f32x4*>(&fu[n][0]);
        float a0 = b_fuse[o], a1 = 0.0f;
        #pragma unroll
        for (int i = 0; i < 15; ++i) {
            const f32x4 wv = wr4[i];
            const f32x4 fv = fr4[i];
            float s = wv[0] * fv[0];
            s = fmaf(wv[1], fv[1], s);
            s = fmaf(wv[2], fv[2], s);
            s = fmaf(wv[3], fv[3], s);
            if (i & 1) a1 += s; else a0 += s;
        }
        fused[n][o] = (a0 + a1) * em[n];
    }
    __syncthreads();

    for (int d = t; d < 3072; d += 256) {
        int n = d / 192, rr = d - n * 192;
        const f32x4* wr4 = reinterpret_cast<const f32x4*>(in_w + rr * 64);
        const f32x4* fr4 = reinterpret_cast<const f32x4*>(&fused[n][0]);
        float a0 = in_b[rr], a1 = 0.0f;
        #pragma unroll
        for (int i = 0; i < 16; ++i) {
            const f32x4 wv = wr4[i];
            const f32x4 fv = fr4[i];
            float s = wv[0] * fv[0];
            s = fmaf(wv[1], fv[1], s);
            s = fmaf(wv[2], fv[2], s);
            s = fmaf(wv[3], fv[3], s);
            if (i & 1) a1 += s; else a0 += s;
        }
        qkvs[n][rr] = a0 + a1;
    }
    __syncthreads();

    for (int d = t; d < 1024; d += 256) {
        int h = d >> 8, i = (d >> 4) & 15, j = d & 15;
        const f32x4* qi = reinterpret_cast<const f32x4*>(&qkvs[i][h * 16]);
        const f32x4* kj = reinterpret_cast<const f32x4*>(&qkvs[j][64 + h * 16]);
        float a = 0.0f;
        #pragma unroll
        for (int q4 = 0; q4 < 4; ++q4) {
            const f32x4 qv = qi[q4];
            const f32x4 kv = kj[q4];
            a = fmaf(qv[0], kv[0], a);
            a = fmaf(qv[1], kv[1], a);
            a = fmaf(qv[2], kv[2], a);
            a = fmaf(qv[3], kv[3], a);
        }
        a *= 0.25f;
        if (em[j] < 0.5f) a = -1e30f;
        sc[h][i][j] = a;
    }
    __syncthreads();

    if (t < 64) {
        int h = t >> 4, i = t & 15;
        float mx = -3.4e38f;
        #pragma unroll
        for (int j = 0; j < 16; ++j) mx = fmaxf(mx, sc[h][i][j]);
        float e[16];
        float s = 0.0f;
        #pragma unroll
        for (int j = 0; j < 16; ++j) { e[j] = expf(sc[h][i][j] - mx); s += e[j]; }
        float inv = 1.0f / s;
        #pragma unroll
        for (int j = 0; j < 16; ++j) sc[h][i][j] = e[j] * inv;
    }
    __syncthreads();

    for (int d = t; d < 1024; d += 256) {
        int n = d >> 6, e = d & 63, h = e >> 4;
        float a = 0.0f;
        #pragma unroll
        for (int j = 0; j < 16; ++j)
            a = fmaf(sc[h][n][j], qkvs[j][128 + e], a);
        ao[n][e] = a;
    }
    __syncthreads();

    for (int d = t; d < 1024; d += 256) {
        int n = d >> 6, o = d & 63;
        const f32x4* wr4 = reinterpret_cast<const f32x4*>(out_w + o * 64);
        const f32x4* ar4 = reinterpret_cast<const f32x4*>(&ao[n][0]);
        float a0 = out_b[o], a1 = 0.0f;
        #pragma unroll
        for (int i = 0; i < 16; ++i) {
            const f32x4 wv = wr4[i];
            const f32x4 av = ar4[i];
            float s = wv[0] * av[0];
            s = fmaf(wv[1], av[1], s);
            s = fmaf(wv[2], av[2], s);
            s = fmaf(wv[3], av[3], s);
            if (i & 1) a1 += s; else a0 += s;
        }
        aoo[n][o] = (a0 + a1) * em[n];
    }
    __syncthreads();

    if (t < 64) {
        float s = 0.0f, ms = 0.0f;
        #pragma unroll
        for (int n = 0; n < 16; ++n) { s += aoo[n][t]; ms += em[n]; }
        p2s[t] = s / (ms + 1e-8f);
    }
    __syncthreads();

    if (t < 64) {
        const f32x4* wr4 = reinterpret_cast<const f32x4*>(w_fc1 + t * 64);
        const f32x4* pr4 = reinterpret_cast<const f32x4*>(p2s);
        float a0 = b_fc1[t], a1 = 0.0f;
        #pragma unroll
        for (int i = 0; i < 16; ++i) {
            const f32x4 wv = wr4[i];
            const f32x4 pv = pr4[i];
            float s = wv[0] * pv[0];
            s = fmaf(wv[1], pv[1], s);
            s = fmaf(wv[2], pv[2], s);
            s = fmaf(wv[3], pv[3], s);
            if (i & 1) a1 += s; else a0 += s;
        }
        hs[t] = fmaxf(a0 + a1, 0.0f);
    }
    __syncthreads();

    if (t < 64) {
        float v = hs[t] * w_fc2[t];
        #pragma unroll
        for (int d2 = 32; d2 >= 1; d2 >>= 1) v += __shfl_xor(v, d2);
        if (t == 0) out[b] = v + b_fc2[0];
    }
}

extern "C" void kernel_launch(void* const* d_in, const int* in_sizes, int n_in,
                              void* d_out, int out_size, void* d_ws, size_t ws_size,
                              hipStream_t stream)
{
    (void)in_sizes; (void)n_in; (void)out_size; (void)ws_size;
    const float* x     = (const float*)d_in[0];
    const float* xmask = (const float*)d_in[1];
    const float* einfo = (const float*)d_in[2];
    const float* emask = (const float*)d_in[3];

    float* xfeatP = (float*)d_ws;                 // 6*512*32 f32 = 393.2 KB
    short* wp3 = (short*)(xfeatP + 6 * 512 * 32); // 3072*8 shorts
    short* wp5 = wp3 + 24576;                     // 5120*8 shorts
    short* wp7 = wp5 + 40960;                     // 7168*8 shorts

    pack_kernel<<<60, 256, 0, stream>>>(
        (const float*)d_in[6], (const float*)d_in[10], (const float*)d_in[14],
        wp3, wp5, wp7);

    branch_fused<<<3072, 256, 0, stream>>>(x, xmask,
        (const float*)d_in[4],  (const float*)d_in[5],  (const float*)d_in[7],  wp3,
        (const float*)d_in[8],  (const float*)d_in[9],  (const float*)d_in[11], wp5,
        (const float*)d_in[12], (const float*)d_in[13], (const float*)d_in[15], wp7,
        (const float*)d_in[16], xfeatP);

    tail_kernel<<<32, 256, 0, stream>>>(xfeatP,
        (const float*)d_in[17], xmask, einfo, emask,
        (const float*)d_in[18], (const float*)d_in[19],
        (const float*)d_in[20], (const float*)d_in[21],
        (const float*)d_in[22], (const float*)d_in[23],
        (const float*)d_in[24], (const float*)d_in[25],
        (const float*)d_in[26], (const float*)d_in[27],
        (const float*)d_in[28], (const float*)d_in[29],
        (const float*)d_in[30], (const float*)d_in[31],
        (float*)d_out);
}

// Round 21
// 69.558 us; speedup vs baseline: 1.6362x; 1.0253x over previous
//
#include <hip/hip_runtime.h>
#include <math.h>

typedef float f32x4 __attribute__((ext_vector_type(4)));
typedef short short8 __attribute__((ext_vector_type(8)));

__device__ __forceinline__ short bf16r(float f) {
    union { float f; unsigned u; } x; x.f = f;
    unsigned u = x.u + 0x7fffu + ((x.u >> 16) & 1u);
    return (short)(u >> 16);
}

// ---------------------------------------------------------------------------
// pack_kernel (16x16x32 format, verified r1-r20) + L3-warm blocks (bx>=60):
// stream the tail's weight working set through f32x4 loads so it resides in
// the die-level Infinity Cache (memory-side, survives kernel boundaries)
// before the tail dispatch. Values kept alive via asm (no DCE).
// ---------------------------------------------------------------------------
template<int K>
__device__ __forceinline__ void pack_branch(const float* __restrict__ w2,
                                            short* __restrict__ wpack, int u) {
    int lane = u & 63;
    int kb   = (u >> 6) & 1;
    int rem  = u >> 7;          // c*K + j
    int j = rem % K, c = rem / K;
    int co  = c * 16 + (lane & 15);
    int cib = kb * 32 + 8 * ((lane >> 4) & 3);
    short8 v;
    #pragma unroll
    for (int i = 0; i < 8; ++i)
        v[i] = bf16r(w2[(co * 64 + (cib + i)) * K + j]);
    *reinterpret_cast<short8*>(wpack + (size_t)u * 8) = v;
}

__global__ __launch_bounds__(256) void pack_kernel(
    const float* __restrict__ w23, const float* __restrict__ w25,
    const float* __restrict__ w27,
    short* __restrict__ wp3, short* __restrict__ wp5, short* __restrict__ wp7,
    const float* __restrict__ in_w,  const float* __restrict__ w_fuse,
    const float* __restrict__ out_w, const float* __restrict__ w_fc1,
    const float* __restrict__ elem_info, const float* __restrict__ emaskp,
    const float* __restrict__ atom_emb,  const float* __restrict__ type_emb,
    const float* __restrict__ xmask)
{
    if (blockIdx.x >= 60) {
        // ---- L3 warming: ~120KB of tail inputs, f32x4 streamed ----
        const int wid = (blockIdx.x - 60) * 256 + threadIdx.x;  // 0..8191
        float acc = 0.0f;
        // in_w 12288 f32 = 3072 x4 | w_fuse 3840 = 960 | out_w 4096 = 1024
        // w_fc1 4096 = 1024 | elem_info 3584 = 896  (total 6976 x4)
        if (wid < 3072) {
            const f32x4 v = reinterpret_cast<const f32x4*>(in_w)[wid];
            acc = v[0] + v[1] + v[2] + v[3];
        } else if (wid < 4032) {
            const f32x4 v = reinterpret_cast<const f32x4*>(w_fuse)[wid - 3072];
            acc = v[0] + v[1] + v[2] + v[3];
        } else if (wid < 5056) {
            const f32x4 v = reinterpret_cast<const f32x4*>(out_w)[wid - 4032];
            acc = v[0] + v[1] + v[2] + v[3];
        } else if (wid < 6080) {
            const f32x4 v = reinterpret_cast<const f32x4*>(w_fc1)[wid - 5056];
            acc = v[0] + v[1] + v[2] + v[3];
        } else if (wid < 6976) {
            const f32x4 v = reinterpret_cast<const f32x4*>(elem_info)[wid - 6080];
            acc = v[0] + v[1] + v[2] + v[3];
        } else if (wid < 7488) {
            acc = emaskp[wid - 6976];          // 512
        } else if (wid < 8000) {
            acc = xmask[wid - 7488];           // 512
        } else if (wid < 8152) {
            int u = wid - 8000;                // atom_emb 760 f32 in 5s
            acc = atom_emb[u * 5] + atom_emb[u * 5 + 4];
        } else if (wid < 8176) {
            acc = type_emb[wid - 8152];        // 24
        }
        asm volatile("" :: "v"(acc));          // keep loads live (rule #17)
        return;
    }
    int tid = blockIdx.x * 256 + threadIdx.x;
    const int n3 = 8 * 3 * 2 * 64;   // 3072
    const int n5 = 8 * 5 * 2 * 64;   // 5120
    const int n7 = 8 * 7 * 2 * 64;   // 7168
    if (tid < n3)                pack_branch<3>(w23, wp3, tid);
    else if (tid < n3 + n5)      pack_branch<5>(w25, wp5, tid - n3);
    else if (tid < n3 + n5 + n7) pack_branch<7>(w27, wp7, tid - n3 - n5);
}

// ---------------------------------------------------------------------------
// mfma_pass2<K,LT0,NLT>: dual-c lt-pass, rolled m-loop + named 1-deep B
// prefetch (spill-safe, r13/r14-verified). One A-read feeds 2 MFMAs.
// ---------------------------------------------------------------------------
template<int K, int LT0, int NLT>
__device__ __forceinline__ void mfma_pass2(
    const short* __restrict__ t1s,
    const short8* __restrict__ wpB0, const short8* __restrict__ wpB1,
    int lane, f32x4* accA, f32x4* accB)
{
    constexpr int PAD = (K - 1) / 2;
    const int lane15 = lane & 15;
    const int g8 = 8 * ((lane >> 4) & 3);
    short8 bA = wpB0[0], bB = wpB1[0];
    #pragma unroll 1
    for (int m = 0; m < 2 * K - 1; ++m) {
        const short8 nA = wpB0[(m + 1) * 64];
        const short8 nB = wpB1[(m + 1) * 64];
        const int j = m >> 1, kb = m & 1;
        const int r = LT0 * 16 + lane15 + 3 + j - PAD;
        const int col = (kb * 32 + g8) ^ ((r & 7) << 3);
        const short* ab = &t1s[r * 64 + col];
        #pragma unroll
        for (int lt = 0; lt < NLT; ++lt) {
            const short8 af = *reinterpret_cast<const short8*>(ab + lt * 1024);
            accA[lt] = __builtin_amdgcn_mfma_f32_16x16x32_bf16(af, bA, accA[lt], 0, 0, 0);
            accB[lt] = __builtin_amdgcn_mfma_f32_16x16x32_bf16(af, bB, accB[lt], 0, 0, 0);
        }
        bA = nA; bB = nB;
    }
    {   // peeled last group
        const int m = 2 * K - 1;
        const int j = m >> 1, kb = m & 1;
        const int r = LT0 * 16 + lane15 + 3 + j - PAD;
        const int col = (kb * 32 + g8) ^ ((r & 7) << 3);
        const short* ab = &t1s[r * 64 + col];
        #pragma unroll
        for (int lt = 0; lt < NLT; ++lt) {
            const short8 af = *reinterpret_cast<const short8*>(ab + lt * 1024);
            accA[lt] = __builtin_amdgcn_mfma_f32_16x16x32_bf16(af, bA, accA[lt], 0, 0, 0);
            accB[lt] = __builtin_amdgcn_mfma_f32_16x16x32_bf16(af, bB, accB[lt], 0, 0, 0);
        }
    }
}

// pool_accum<GV,LT0,NLT>: C/D col=lane&15, row=4g+r4 (verified r1-r20).
template<int GV, int LT0, int NLT>
__device__ __forceinline__ void pool_accum(const f32x4* acc, float bb, float* pb) {
    #pragma unroll
    for (int lt = 0; lt < NLT; ++lt) {
        #pragma unroll
        for (int r4 = 0; r4 < 4; ++r4) {
            const int l = (LT0 + lt) * 16 + 4 * GV + r4;   // compile-time
            if (l < 200)
                pb[l / 20] += fmaxf(acc[lt][r4] + bb, 0.0f);
        }
    }
}

template<int K, int LT0, int NLT>
__device__ __forceinline__ void do_pass2(
    const short* __restrict__ t1s,
    const short8* __restrict__ wpB0, const short8* __restrict__ wpB1,
    int lane, float bb0, float bb1, float* pb0, float* pb1)
{
    const int g = (lane >> 4) & 3;
    f32x4 accA[NLT], accB[NLT];
    #pragma unroll
    for (int i = 0; i < NLT; ++i) {
        f32x4 z = {0.f, 0.f, 0.f, 0.f};
        accA[i] = z; accB[i] = z;
    }
    mfma_pass2<K, LT0, NLT>(t1s, wpB0, wpB1, lane, accA, accB);
    if      (g == 0) { pool_accum<0, LT0, NLT>(accA, bb0, pb0); pool_accum<0, LT0, NLT>(accB, bb1, pb1); }
    else if (g == 1) { pool_accum<1, LT0, NLT>(accA, bb0, pb0); pool_accum<1, LT0, NLT>(accB, bb1, pb1); }
    else if (g == 2) { pool_accum<2, LT0, NLT>(accA, bb0, pb0); pool_accum<2, LT0, NLT>(accB, bb1, pb1); }
    else             { pool_accum<3, LT0, NLT>(accA, bb0, pb0); pool_accum<3, LT0, NLT>(accB, bb1, pb1); }
}

// ---------------------------------------------------------------------------
// branch_body<K>: unchanged from r13/r14 (verified clean + fastest).
// ---------------------------------------------------------------------------
template<int K>
__device__ __forceinline__ void branch_body(
    const int bn, const int t,
    const float* __restrict__ x,
    const float* __restrict__ w1, const float* __restrict__ b1,
    const float* __restrict__ b2, const short* __restrict__ wpack,
    const float* __restrict__ w_xfc_br, float* __restrict__ xfeatP_br,
    float* xs, short* t1s, float* pooled_s, float* b2s)
{
    constexpr int PAD = (K - 1) / 2;
    const int lane = t & 63;
    const int w    = t >> 6;            // 0..3, owns c = 2w, 2w+1
    const int lane15 = lane & 15;

    if (t < 208) xs[t] = 0.0f;
    for (int idx = t; idx < 32 * 64; idx += 256) {  // halo rows 0..2, 203..231
        int rr = idx >> 6;
        int row = (rr < 3) ? rr : (200 + rr);
        t1s[row * 64 + (idx & 63)] = 0;
    }
    if (t < 128) b2s[t] = b2[t];
    __syncthreads();

    if (t < 200) xs[3 + t] = x[bn * 200 + t];
    __syncthreads();

    // conv1, register-window (wave-uniform broadcast reads)
    {
        float w1_0 = w1[lane * K + 0], w1_1 = w1[lane * K + 1], w1_2 = w1[lane * K + 2];
        float w1_3 = 0.f, w1_4 = 0.f, w1_5 = 0.f, w1_6 = 0.f;
        if (K > 3) { w1_3 = w1[lane * K + 3]; w1_4 = w1[lane * K + 4]; }
        if (K > 5) { w1_5 = w1[lane * K + 5]; w1_6 = w1[lane * K + 6]; }
        const float b1r = b1[lane];
        #pragma unroll 1
        for (int ch = 0; ch < 2; ++ch) {
            const int lb = 50 * w + 25 * ch;       // wave-uniform base
            float xr[31];
            #pragma unroll
            for (int i = 0; i < 31; ++i) xr[i] = xs[lb + i];   // broadcast reads
            #pragma unroll
            for (int ll = 0; ll < 25; ++ll) {
                float a = b1r;
                a = fmaf(w1_0, xr[ll + 3 - PAD + 0], a);
                a = fmaf(w1_1, xr[ll + 3 - PAD + 1], a);
                a = fmaf(w1_2, xr[ll + 3 - PAD + 2], a);
                if (K > 3) {
                    a = fmaf(w1_3, xr[ll + 3 - PAD + 3], a);
                    a = fmaf(w1_4, xr[ll + 3 - PAD + 4], a);
                }
                if (K > 5) {
                    a = fmaf(w1_5, xr[ll + 3 - PAD + 5], a);
                    a = fmaf(w1_6, xr[ll + 3 - PAD + 6], a);
                }
                const int row = lb + ll + 3;
                t1s[row * 64 + (lane ^ ((row & 7) << 3))] = bf16r(fmaxf(a, 0.0f));
            }
        }
    }
    __syncthreads();

    const int c0 = 2 * w, c1 = 2 * w + 1;
    const int coA = c0 * 16 + lane15, coB = c1 * 16 + lane15;
    const float bb0 = b2s[coA], bb1 = b2s[coB];
    const short8* wpB0 = reinterpret_cast<const short8*>(wpack)
                         + (size_t)(c0 * 2 * K) * 64 + lane;
    const short8* wpB1 = reinterpret_cast<const short8*>(wpack)
                         + (size_t)(c1 * 2 * K) * 64 + lane;

    float pb0[10], pb1[10];
    #pragma unroll
    for (int b = 0; b < 10; ++b) { pb0[b] = 0.0f; pb1[b] = 0.0f; }

    do_pass2<K, 0, 7>(t1s, wpB0, wpB1, lane, bb0, bb1, pb0, pb1);
    do_pass2<K, 7, 6>(t1s, wpB0, wpB1, lane, bb0, bb1, pb0, pb1);

    #pragma unroll
    for (int b = 0; b < 10; ++b) {
        pb0[b] += __shfl_xor(pb0[b], 16);
        pb0[b] += __shfl_xor(pb0[b], 32);
        pb1[b] += __shfl_xor(pb1[b], 16);
        pb1[b] += __shfl_xor(pb1[b], 32);
    }
    if (lane < 16) {
        #pragma unroll
        for (int b = 0; b < 10; ++b) {
            pooled_s[coA * 10 + b] = pb0[b];
            pooled_s[coB * 10 + b] = pb1[b];
        }
    }
    __syncthreads();

    // xfc partial: o = t>>3 (0..31), part = t&7; coalesced f32x4
    {
        const int o = t >> 3, part = t & 7;
        const f32x4* wr4 = reinterpret_cast<const f32x4*>(w_xfc_br + o * 3840);
        const f32x4* pp4 = reinterpret_cast<const f32x4*>(pooled_s);
        float s0 = 0.0f, s1 = 0.0f;
        #pragma unroll
        for (int i = 0; i < 40; ++i) {
            const f32x4 wv = wr4[part + 8 * i];
            const f32x4 pv = pp4[part + 8 * i];
            float s = wv[0] * pv[0];
            s = fmaf(wv[1], pv[1], s);
            s = fmaf(wv[2], pv[2], s);
            s = fmaf(wv[3], pv[3], s);
            if (i & 1) s1 += s; else s0 += s;
        }
        float a = s0 + s1;
        a += __shfl_xor(a, 1);
        a += __shfl_xor(a, 2);
        a += __shfl_xor(a, 4);
        if (part == 0) xfeatP_br[bn * 32 + o] = a * 0.05f;
    }
}

__global__ __launch_bounds__(256, 4) void branch_fused(
    const float* __restrict__ x, const float* __restrict__ xmask,
    const float* __restrict__ w1_3, const float* __restrict__ b1_3,
    const float* __restrict__ b2_3, const short* __restrict__ wp3,
    const float* __restrict__ w1_5, const float* __restrict__ b1_5,
    const float* __restrict__ b2_5, const short* __restrict__ wp5,
    const float* __restrict__ w1_7, const float* __restrict__ b1_7,
    const float* __restrict__ b2_7, const short* __restrict__ wp7,
    const float* __restrict__ w_xfc, float* __restrict__ xfeatP)
{
    __shared__ float xs[208];
    __shared__ short t1s[232 * 64];
    __shared__ __align__(16) float pooled_s[1280];
    __shared__ float b2s[128];

    const int bx = blockIdx.x;
    const int br = bx % 3;          // interleave K=3/5/7 in every generation
    const int bn = bx / 3;
    const int t  = threadIdx.x;

    if (xmask[bn] == 0.0f) return;  // tail multiplies row by 0 -> exact

    if (br == 0)
        branch_body<3>(bn, t, x, w1_3, b1_3, b2_3, wp3,
                       w_xfc,        xfeatP,             xs, t1s, pooled_s, b2s);
    else if (br == 1)
        branch_body<5>(bn, t, x, w1_5, b1_5, b2_5, wp5,
                       w_xfc + 1280, xfeatP + 512 * 32,  xs, t1s, pooled_s, b2s);
    else
        branch_body<7>(bn, t, x, w1_7, b1_7, b2_7, wp7,
                       w_xfc + 2560, xfeatP + 1024 * 32, xs, t1s, pooled_s, b2s);
}

// ---------------------------------------------------------------------------
// Tail: r14 numerics verbatim (best measured).
// ---------------------------------------------------------------------------
__global__ __launch_bounds__(256, 1) void tail_kernel(
    const float* __restrict__ xfeatP,     // (3, 512, 32)
    const float* __restrict__ b_xfc,      // (32,)
    const float* __restrict__ xmaskp,     // (512,)
    const float* __restrict__ elem_info,  // (32, 16, 7)
    const float* __restrict__ emaskp,     // (32, 16)
    const float* __restrict__ w_float, const float* __restrict__ b_float,
    const float* __restrict__ atom_emb, const float* __restrict__ type_emb,
    const float* __restrict__ w_fuse,  const float* __restrict__ b_fuse,
    const float* __restrict__ in_w,    const float* __restrict__ in_b,
    const float* __restrict__ out_w,   const float* __restrict__ out_b,
    const float* __restrict__ w_fc1,   const float* __restrict__ b_fc1,
    const float* __restrict__ w_fc2,   const float* __restrict__ b_fc2,
    float* __restrict__ out)              // (32,)
{
    const int b = blockIdx.x;
    const int t = threadIdx.x;

    __shared__ __align__(16) float fu[16][60];
    __shared__ __align__(16) float fused[16][64];
    __shared__ __align__(16) float qkvs[16][196];  // padded: 784B = 49*16
    __shared__ __align__(16) float sc[4][16][16];
    __shared__ __align__(16) float ao[16][64];
    __shared__ __align__(16) float aoo[16][64];
    __shared__ float p2s[64];
    __shared__ float hs[64];
    __shared__ float em[16];

    if (t < 16) em[t] = emaskp[b * 16 + t];

    for (int d = t; d < 512; d += 256) {
        int n = d >> 5, o = d & 31;
        const int bn = b * 16 + n;
        float a = xfeatP[bn * 32 + o]
                + xfeatP[(512 + bn) * 32 + o]
                + xfeatP[(1024 + bn) * 32 + o];
        fu[n][o] = (a + b_xfc[o]) * xmaskp[bn];
    }
    {
        int n = t >> 4, slot = t & 15;
        float m  = emaskp[b * 16 + n];
        float vE = (m >= 0.5f) ? 1.0f : 0.0f;
        const float* ei = elem_info + (b * 16 + n) * 7;
        float a = b_float[slot];
        #pragma unroll
        for (int i = 0; i < 5; ++i)
            a = fmaf(ei[i] * m, w_float[slot * 5 + i], a);
        fu[n][32 + slot] = fmaxf(a, 0.0f) * vE * m;

        int an = (int)(ei[5] * m);
        int et = (int)(ei[6] * m);
        float take = (vE != 0.0f && an >= 1 && an <= 94) ? 1.0f : 0.0f;
        int anc = an < 0 ? 0 : (an > 94 ? 94 : an);
        int etc = et < 0 ? 0 : (et > 5 ? 5 : et);
        if (slot < 8)
            fu[n][48 + slot] = atom_emb[anc * 8 + slot] * take * m;
        else if (slot < 12)
            fu[n][56 + (slot - 8)] = type_emb[etc * 4 + (slot - 8)] * take * m;
    }
    __syncthreads();

    for (int d = t; d < 1024; d += 256) {
        int n = d >> 6, o = d & 63;
        const f32x4* wr4 = reinterpret_cast<const f32x4*>(w_fuse + o * 60);
        const f32x4* fr4 = reinterpret_cast<const f32x4*>(&fu[n][0]);
        float a0 = b_fuse[o], a1 = 0.0f;
        #pragma unroll
        for (int i = 0; i < 15; ++i) {
            const f32x4 wv = wr4[i];
            const f32x4 fv = fr4[i];
            float s = wv[0] * fv[0];
            s = fmaf(wv[1], fv[1], s);
            s = fmaf(wv[2], fv[2], s);
            s = fmaf(wv[3], fv[3], s);
            if (i & 1) a1 += s; else a0 += s;
        }
        fused[n][o] = (a0 + a1) * em[n];
    }
    __syncthreads();

    for (int d = t; d < 3072; d += 256) {
        int n = d / 192, rr = d - n * 192;
        const f32x4* wr4 = reinterpret_cast<const f32x4*>(in_w + rr * 64);
        const f32x4* fr4 = reinterpret_cast<const f32x4*>(&fused[n][0]);
        float a0 = in_b[rr], a1 = 0.0f;
        #pragma unroll
        for (int i = 0; i < 16; ++i) {
            const f32x4 wv = wr4[i];
            const f32x4 fv = fr4[i];
            float s = wv[0] * fv[0];
            s = fmaf(wv[1], fv[1], s);
            s = fmaf(wv[2], fv[2], s);
            s = fmaf(wv[3], fv[3], s);
            if (i & 1) a1 += s; else a0 += s;
        }
        qkvs[n][rr] = a0 + a1;
    }
    __syncthreads();

    for (int d = t; d < 1024; d += 256) {
        int h = d >> 8, i = (d >> 4) & 15, j = d & 15;
        const f32x4* qi = reinterpret_cast<const f32x4*>(&qkvs[i][h * 16]);
        const f32x4* kj = reinterpret_cast<const f32x4*>(&qkvs[j][64 + h * 16]);
        float a = 0.0f;
        #pragma unroll
        for (int q4 = 0; q4 < 4; ++q4) {
            const f32x4 qv = qi[q4];
            const f32x4 kv = kj[q4];
            a = fmaf(qv[0], kv[0], a);
            a = fmaf(qv[1], kv[1], a);
            a = fmaf(qv[2], kv[2], a);
            a = fmaf(qv[3], kv[3], a);
        }
        a *= 0.25f;
        if (em[j] < 0.5f) a = -1e30f;
        sc[h][i][j] = a;
    }
    __syncthreads();

    if (t < 64) {
        int h = t >> 4, i = t & 15;
        float mx = -3.4e38f;
        #pragma unroll
        for (int j = 0; j < 16; ++j) mx = fmaxf(mx, sc[h][i][j]);
        float e[16];
        float s = 0.0f;
        #pragma unroll
        for (int j = 0; j < 16; ++j) { e[j] = expf(sc[h][i][j] - mx); s += e[j]; }
        float inv = 1.0f / s;
        #pragma unroll
        for (int j = 0; j < 16; ++j) sc[h][i][j] = e[j] * inv;
    }
    __syncthreads();

    for (int d = t; d < 1024; d += 256) {
        int n = d >> 6, e = d & 63, h = e >> 4;
        float a = 0.0f;
        #pragma unroll
        for (int j = 0; j < 16; ++j)
            a = fmaf(sc[h][n][j], qkvs[j][128 + e], a);
        ao[n][e] = a;
    }
    __syncthreads();

    for (int d = t; d < 1024; d += 256) {
        int n = d >> 6, o = d & 63;
        const f32x4* wr4 = reinterpret_cast<const f32x4*>(out_w + o * 64);
        const f32x4* ar4 = reinterpret_cast<const f32x4*>(&ao[n][0]);
        float a0 = out_b[o], a1 = 0.0f;
        #pragma unroll
        for (int i = 0; i < 16; ++i) {
            const f32x4 wv = wr4[i];
            const f32x4 av = ar4[i];
            float s = wv[0] * av[0];
            s = fmaf(wv[1], av[1], s);
            s = fmaf(wv[2], av[2], s);
            s = fmaf(wv[3], av[3], s);
            if (i & 1) a1 += s; else a0 += s;
        }
        aoo[n][o] = (a0 + a1) * em[n];
    }
    __syncthreads();

    if (t < 64) {
        float s = 0.0f, ms = 0.0f;
        #pragma unroll
        for (int n = 0; n < 16; ++n) { s += aoo[n][t]; ms += em[n]; }
        p2s[t] = s / (ms + 1e-8f);
    }
    __syncthreads();

    if (t < 64) {
        const f32x4* wr4 = reinterpret_cast<const f32x4*>(w_fc1 + t * 64);
        const f32x4* pr4 = reinterpret_cast<const f32x4*>(p2s);
        float a0 = b_fc1[t], a1 = 0.0f;
        #pragma unroll
        for (int i = 0; i < 16; ++i) {
            const f32x4 wv = wr4[i];
            const f32x4 pv = pr4[i];
            float s = wv[0] * pv[0];
            s = fmaf(wv[1], pv[1], s);
            s = fmaf(wv[2], pv[2], s);
            s = fmaf(wv[3], pv[3], s);
            if (i & 1) a1 += s; else a0 += s;
        }
        hs[t] = fmaxf(a0 + a1, 0.0f);
    }
    __syncthreads();

    if (t < 64) {
        float v = hs[t] * w_fc2[t];
        #pragma unroll
        for (int d2 = 32; d2 >= 1; d2 >>= 1) v += __shfl_xor(v, d2);
        if (t == 0) out[b] = v + b_fc2[0];
    }
}

extern "C" void kernel_launch(void* const* d_in, const int* in_sizes, int n_in,
                              void* d_out, int out_size, void* d_ws, size_t ws_size,
                              hipStream_t stream)
{
    (void)in_sizes; (void)n_in; (void)out_size; (void)ws_size;
    const float* x     = (const float*)d_in[0];
    const float* xmask = (const float*)d_in[1];
    const float* einfo = (const float*)d_in[2];
    const float* emask = (const float*)d_in[3];

    float* xfeatP = (float*)d_ws;                 // 3*512*32 f32 = 196.6 KB
    short* wp3 = (short*)(xfeatP + 3 * 512 * 32); // 3072*8 shorts
    short* wp5 = wp3 + 24576;                     // 5120*8 shorts
    short* wp7 = wp5 + 40960;                     // 7168*8 shorts

    pack_kernel<<<92, 256, 0, stream>>>(
        (const float*)d_in[6], (const float*)d_in[10], (const float*)d_in[14],
        wp3, wp5, wp7,
        (const float*)d_in[24], (const float*)d_in[22],
        (const float*)d_in[26], (const float*)d_in[28],
        einfo, emask,
        (const float*)d_in[20], (const float*)d_in[21], xmask);

    branch_fused<<<1536, 256, 0, stream>>>(x, xmask,
        (const float*)d_in[4],  (const float*)d_in[5],  (const float*)d_in[7],  wp3,
        (const float*)d_in[8],  (const float*)d_in[9],  (const float*)d_in[11], wp5,
        (const float*)d_in[12], (const float*)d_in[13], (const float*)d_in[15], wp7,
        (const float*)d_in[16], xfeatP);

    tail_kernel<<<32, 256, 0, stream>>>(xfeatP,
        (const float*)d_in[17], xmask, einfo, emask,
        (const float*)d_in[18], (const float*)d_in[19],
        (const float*)d_in[20], (const float*)d_in[21],
        (const float*)d_in[22], (const float*)d_in[23],
        (const float*)d_in[24], (const float*)d_in[25],
        (const float*)d_in[26], (const float*)d_in[27],
        (const float*)d_in[28], (const float*)d_in[29],
        (const float*)d_in[30], (const float*)d_in[31],
        (float*)d_out);
}